// Round 3
// baseline (3644.250 us; speedup 1.0000x reference)
//
#include <hip/hip_runtime.h>

// Problem constants
#define TOKENS 4096      // B*S
#define BATCH  16
#define SEQ    256
#define Hdim   768
#define FFdim  3072
#define NHEAD  12
#define NLBL   9
#define NLAYER 12

typedef unsigned short u16;
typedef __attribute__((ext_vector_type(8))) short short8;   // 8 bf16 (4 VGPRs) MFMA frag
typedef __attribute__((ext_vector_type(4))) float floatx4;  // MFMA acc

__device__ __forceinline__ float bf2f(u16 u) {
    union { unsigned int i; float f; } c; c.i = ((unsigned int)u) << 16; return c.f;
}
__device__ __forceinline__ u16 f2bf(float f) {
    union { float f; unsigned int i; } c; c.f = f;
    unsigned int u = c.i;
    u = u + 0x7fffu + ((u >> 16) & 1u);   // RNE
    return (u16)(u >> 16);
}

// ---------------------------------------------------------------------------
// 128x128-tile GEMM:  out = A(M x K) @ B(K x N) + bias
// A row-major bf16 (internal activations), B row-major FLOAT32 (weights as
// given), converted to bf16 during LDS staging.
// MODE 0: bf16 out; MODE 1: bf16 out with tanh-GELU; MODE 2: f32 out.
// LDS rows padded to 40 halves (80 B): b128 reads 16B-aligned.
// ---------------------------------------------------------------------------
template<int MODE>
__device__ __forceinline__ void gemm_body(const u16* __restrict__ Ag, const float* __restrict__ Bg,
                                          const float* __restrict__ bias, void* __restrict__ outp,
                                          int N, int K, int m0, int n0)
{
    __shared__ u16 As[128 * 40];
    __shared__ u16 Bt[128 * 40];   // B tile transposed: Bt[n][k]
    const int tid  = threadIdx.x;
    const int lane = tid & 63, w = tid >> 6;
    const int wr = w >> 1, wc = w & 1;
    const int quad = lane >> 4, l16 = lane & 15;

    const floatx4 vzero = {0.f, 0.f, 0.f, 0.f};
    floatx4 acc[4][4];
#pragma unroll
    for (int i = 0; i < 4; i++)
#pragma unroll
        for (int j = 0; j < 4; j++) acc[i][j] = vzero;

    for (int k0 = 0; k0 < K; k0 += 32) {
        // stage A tile 128x32 (bf16, vector loads, aligned b128 LDS writes)
#pragma unroll
        for (int i = 0; i < 2; i++) {
            int c = tid + i * 256;
            int row = c >> 2, cc = (c & 3) << 3;
            uint4 dv = *(const uint4*)(Ag + (size_t)(m0 + row) * K + k0 + cc);
            *(uint4*)(&As[row * 40 + cc]) = dv;
        }
        // stage B tile 32x128 transposed with f32->bf16 conversion
#pragma unroll
        for (int i = 0; i < 2; i++) {
            int c = tid + i * 256;
            int n = c & 127, kc8 = (c >> 7) << 3;
            union { u16 h[8]; uint4 v; } tb;
#pragma unroll
            for (int e = 0; e < 8; e++) tb.h[e] = f2bf(Bg[(size_t)(k0 + kc8 + e) * N + n0 + n]);
            *(uint4*)(&Bt[n * 40 + kc8]) = tb.v;
        }
        __syncthreads();
        short8 af[4], bfr[4];
#pragma unroll
        for (int mt = 0; mt < 4; mt++) af[mt] = *(const short8*)(&As[(wr * 64 + mt * 16 + l16) * 40 + quad * 8]);
#pragma unroll
        for (int nt = 0; nt < 4; nt++) bfr[nt] = *(const short8*)(&Bt[(wc * 64 + nt * 16 + l16) * 40 + quad * 8]);
#pragma unroll
        for (int mt = 0; mt < 4; mt++)
#pragma unroll
            for (int nt = 0; nt < 4; nt++)
                acc[mt][nt] = __builtin_amdgcn_mfma_f32_16x16x32_bf16(af[mt], bfr[nt], acc[mt][nt], 0, 0, 0);
        __syncthreads();
    }
    // epilogue: C/D layout col=lane&15, row=quad*4+reg  [m89/m91 verified]
#pragma unroll
    for (int mt = 0; mt < 4; mt++) {
#pragma unroll
        for (int nt = 0; nt < 4; nt++) {
            int col = n0 + wc * 64 + nt * 16 + l16;
            float bv = bias[col];
#pragma unroll
            for (int r = 0; r < 4; r++) {
                int row = m0 + wr * 64 + mt * 16 + quad * 4 + r;
                float vv = acc[mt][nt][r] + bv;
                if (MODE == 1) {
                    float t = 0.7978845608028654f * (vv + 0.044715f * vv * vv * vv);
                    vv = 0.5f * vv * (1.0f + tanhf(t));
                }
                if (MODE == 2) ((float*)outp)[(size_t)row * N + col] = vv;
                else          ((u16*)outp)[(size_t)row * N + col] = f2bf(vv);
            }
        }
    }
}

template<int MODE>
__global__ __launch_bounds__(256) void k_gemm(const u16* __restrict__ Ag, const float* __restrict__ Bg,
                                              const float* __restrict__ bias, void* __restrict__ outp,
                                              int N, int K)
{
    gemm_body<MODE>(Ag, Bg, bias, outp, N, K, blockIdx.y * 128, blockIdx.x * 128);
}

// Fused QKV: grid.z selects which projection
__global__ __launch_bounds__(256) void k_qkv(const u16* __restrict__ x,
                                             const float* __restrict__ Wq, const float* __restrict__ Wk, const float* __restrict__ Wv,
                                             const float* __restrict__ bq, const float* __restrict__ bk, const float* __restrict__ bv,
                                             u16* __restrict__ qo, u16* __restrict__ ko, u16* __restrict__ vo)
{
    const float* W; const float* bb; u16* o;
    if (blockIdx.z == 0)      { W = Wq; bb = bq; o = qo; }
    else if (blockIdx.z == 1) { W = Wk; bb = bk; o = ko; }
    else                      { W = Wv; bb = bv; o = vo; }
    gemm_body<0>(x, W, bb, o, Hdim, Hdim, blockIdx.y * 128, blockIdx.x * 128);
}

// ---------------------------------------------------------------------------
// Embedding gather + LayerNorm (all-f32 inputs). One block per token.
// Writes f32 residual stream + bf16 mirror for GEMMs.
// ---------------------------------------------------------------------------
__global__ __launch_bounds__(256) void k_embed(const int* __restrict__ wid, const int* __restrict__ tidv,
                                               const float* __restrict__ we, const float* __restrict__ pe, const float* __restrict__ te,
                                               const float* __restrict__ g, const float* __restrict__ bb,
                                               float* __restrict__ xf, u16* __restrict__ xh)
{
    int i = blockIdx.x; int s = i & 255;
    int t = threadIdx.x;
    int wv = wid[i], tv = tidv[i];
    float e[3]; float sum = 0.f, sq = 0.f;
#pragma unroll
    for (int r = 0; r < 3; r++) {
        int j = t + r * 256;
        float x = we[(size_t)wv * Hdim + j] + pe[s * Hdim + j] + te[tv * Hdim + j];
        e[r] = x; sum += x; sq += x * x;
    }
    __shared__ float red[8];
    for (int off = 32; off; off >>= 1) { sum += __shfl_xor(sum, off); sq += __shfl_xor(sq, off); }
    if ((t & 63) == 0) { red[t >> 6] = sum; red[4 + (t >> 6)] = sq; }
    __syncthreads();
    sum = red[0] + red[1] + red[2] + red[3];
    sq  = red[4] + red[5] + red[6] + red[7];
    float mean = sum * (1.0f / Hdim);
    float var  = sq * (1.0f / Hdim) - mean * mean;
    float rstd = rsqrtf(var + 1e-12f);
#pragma unroll
    for (int r = 0; r < 3; r++) {
        int j = t + r * 256;
        float v = (e[r] - mean) * rstd * g[j] + bb[j];
        xf[(size_t)i * Hdim + j] = v;
        xh[(size_t)i * Hdim + j] = f2bf(v);
    }
}

// residual add + LayerNorm (f32), updates xf in place, writes bf16 mirror
__global__ __launch_bounds__(256) void k_addln(float* __restrict__ xf, const float* __restrict__ y,
                                               const float* __restrict__ g, const float* __restrict__ bb,
                                               u16* __restrict__ xh)
{
    int i = blockIdx.x; int t = threadIdx.x;
    float e[3]; float sum = 0.f, sq = 0.f;
#pragma unroll
    for (int r = 0; r < 3; r++) {
        int j = t + r * 256;
        float x = xf[(size_t)i * Hdim + j] + y[(size_t)i * Hdim + j];
        e[r] = x; sum += x; sq += x * x;
    }
    __shared__ float red[8];
    for (int off = 32; off; off >>= 1) { sum += __shfl_xor(sum, off); sq += __shfl_xor(sq, off); }
    if ((t & 63) == 0) { red[t >> 6] = sum; red[4 + (t >> 6)] = sq; }
    __syncthreads();
    sum = red[0] + red[1] + red[2] + red[3];
    sq  = red[4] + red[5] + red[6] + red[7];
    float mean = sum * (1.0f / Hdim);
    float var  = sq * (1.0f / Hdim) - mean * mean;
    float rstd = rsqrtf(var + 1e-12f);
#pragma unroll
    for (int r = 0; r < 3; r++) {
        int j = t + r * 256;
        float v = (e[r] - mean) * rstd * g[j] + bb[j];
        xf[(size_t)i * Hdim + j] = v;
        xh[(size_t)i * Hdim + j] = f2bf(v);
    }
}

// ---------------------------------------------------------------------------
// Fused MFMA attention (unchanged: q/k/v are internal bf16 buffers).
// One block per (b, head). 4 waves; wave w owns queries w*64..w*64+63.
// ---------------------------------------------------------------------------
__global__ __launch_bounds__(256, 2) void k_attn(const u16* __restrict__ qg, const u16* __restrict__ kg,
                                                 const u16* __restrict__ vg, const int* __restrict__ maskg,
                                                 u16* __restrict__ ctx)
{
    __shared__ u16 Vt[64 * 264];       // Vt[d][key], rows padded to 264 halves
    __shared__ u16 Ps[4 * 64 * 40];    // per-wave P chunk, rows padded to 40
    __shared__ float madd[256];
    int bh = blockIdx.x; int b = bh / NHEAD; int h = bh - b * NHEAD;
    int tid = threadIdx.x; int lane = tid & 63; int w = tid >> 6;
    int quad = lane >> 4, l16 = lane & 15;
    size_t base = (size_t)b * SEQ * Hdim + h * 64;

    // stage V transposed
#pragma unroll
    for (int i = 0; i < 8; i++) {
        int c = tid + i * 256; int key = c >> 3; int cc = (c & 7) << 3;
        uint4 vv = *(const uint4*)(vg + base + (size_t)key * Hdim + cc);
        const u16* p16 = (const u16*)&vv;
#pragma unroll
        for (int e = 0; e < 8; e++) Vt[(cc + e) * 264 + key] = p16[e];
    }
    madd[tid] = (1.0f - (float)maskg[b * SEQ + tid]) * -10000.0f;
    __syncthreads();

    // Q fragments in registers: A[m=lane&15][k=quad*8+j]
    short8 aq[4][2];
#pragma unroll
    for (int mt = 0; mt < 4; mt++)
#pragma unroll
        for (int kf = 0; kf < 2; kf++)
            aq[mt][kf] = *(const short8*)(qg + base + (size_t)(w * 64 + mt * 16 + l16) * Hdim + kf * 32 + quad * 8);

    const floatx4 vzero = {0.f, 0.f, 0.f, 0.f};
    floatx4 acc[4][4];
    float l_run[4][4];
#pragma unroll
    for (int a = 0; a < 4; a++)
#pragma unroll
        for (int r = 0; r < 4; r++) { acc[a][r] = vzero; l_run[a][r] = 0.f; }

    u16* Pw = &Ps[w * 64 * 40];

    for (int kc = 0; kc < 8; kc++) {
        floatx4 sc[4][2];
#pragma unroll
        for (int mt = 0; mt < 4; mt++) { sc[mt][0] = vzero; sc[mt][1] = vzero; }
#pragma unroll
        for (int kf = 0; kf < 2; kf++) {
            short8 bk_[2];
#pragma unroll
            for (int nt = 0; nt < 2; nt++)
                bk_[nt] = *(const short8*)(kg + base + (size_t)(kc * 32 + nt * 16 + l16) * Hdim + kf * 32 + quad * 8);
#pragma unroll
            for (int mt = 0; mt < 4; mt++)
#pragma unroll
                for (int nt = 0; nt < 2; nt++)
                    sc[mt][nt] = __builtin_amdgcn_mfma_f32_16x16x32_bf16(aq[mt][kf], bk_[nt], sc[mt][nt], 0, 0, 0);
        }
        float madd0 = madd[kc * 32 + l16];
        float madd1 = madd[kc * 32 + 16 + l16];
#pragma unroll
        for (int mt = 0; mt < 4; mt++) {
#pragma unroll
            for (int r = 0; r < 4; r++) {
                float p0 = __expf(sc[mt][0][r] * 0.125f + madd0);
                float p1 = __expf(sc[mt][1][r] * 0.125f + madd1);
                float ls = p0 + p1;
#pragma unroll
                for (int off = 1; off < 16; off <<= 1) ls += __shfl_xor(ls, off);
                l_run[mt][r] += ls;
                int row = mt * 16 + quad * 4 + r;
                Pw[row * 40 + l16]      = f2bf(p0);
                Pw[row * 40 + 16 + l16] = f2bf(p1);
            }
        }
        short8 ap[4], bv_[4];
#pragma unroll
        for (int nt = 0; nt < 4; nt++)
            bv_[nt] = *(const short8*)(&Vt[(nt * 16 + l16) * 264 + kc * 32 + quad * 8]);
#pragma unroll
        for (int mt = 0; mt < 4; mt++)
            ap[mt] = *(const short8*)(&Pw[(mt * 16 + l16) * 40 + quad * 8]);
#pragma unroll
        for (int mt = 0; mt < 4; mt++)
#pragma unroll
            for (int nt = 0; nt < 4; nt++)
                acc[mt][nt] = __builtin_amdgcn_mfma_f32_16x16x32_bf16(ap[mt], bv_[nt], acc[mt][nt], 0, 0, 0);
    }
#pragma unroll
    for (int mt = 0; mt < 4; mt++)
#pragma unroll
        for (int r = 0; r < 4; r++) {
            float inv = 1.0f / l_run[mt][r];
            int sq_ = w * 64 + mt * 16 + quad * 4 + r;
#pragma unroll
            for (int nt = 0; nt < 4; nt++)
                ctx[base + (size_t)sq_ * Hdim + nt * 16 + l16] = f2bf(acc[mt][nt][r] * inv);
        }
}

// valid-token compaction indices (stable)
__global__ void k_compact(const int* __restrict__ vm, int* __restrict__ counts, int* __restrict__ srcidx)
{
    int b = blockIdx.x;
    if (threadIdx.x == 0) {
        int c = 0;
        for (int s = 0; s < SEQ; s++)
            if (vm[b * SEQ + s]) { srcidx[b * SEQ + c] = s; c++; }
        counts[b] = c;
    }
}

// classifier head: one wave per output row; rows >= counts[b] get softmax(cls_b)
__global__ __launch_bounds__(256) void k_cls(const u16* __restrict__ x, const int* __restrict__ counts,
                                             const int* __restrict__ srcidx, const float* __restrict__ Wc,
                                             const float* __restrict__ bc, float* __restrict__ out)
{
    int w = threadIdx.x >> 6, lane = threadIdx.x & 63;
    int row = blockIdx.x * 4 + w;
    int b = row >> 8, s = row & 255;
    float acc[NLBL];
#pragma unroll
    for (int n = 0; n < NLBL; n++) acc[n] = 0.f;
    int cnt = counts[b];
    if (s < cnt) {
        int src = srcidx[b * SEQ + s];
        const u16* xr = x + (size_t)(b * SEQ + src) * Hdim;
        for (int j = lane; j < Hdim; j += 64) {
            float xv = bf2f(xr[j]);
#pragma unroll
            for (int n = 0; n < NLBL; n++) acc[n] += xv * Wc[j * NLBL + n];
        }
    }
#pragma unroll
    for (int n = 0; n < NLBL; n++)
        for (int off = 32; off; off >>= 1) acc[n] += __shfl_xor(acc[n], off);
    if (lane == 0) {
        float lg[NLBL]; float mx = -1e30f;
#pragma unroll
        for (int n = 0; n < NLBL; n++) { lg[n] = acc[n] + bc[n]; mx = fmaxf(mx, lg[n]); }
        float se = 0.f;
#pragma unroll
        for (int n = 0; n < NLBL; n++) { lg[n] = __expf(lg[n] - mx); se += lg[n]; }
        float inv = 1.0f / se;
#pragma unroll
        for (int n = 0; n < NLBL; n++) out[(size_t)row * NLBL + n] = lg[n] * inv;
    }
}

extern "C" void kernel_launch(void* const* d_in, const int* in_sizes, int n_in,
                              void* d_out, int out_size, void* d_ws, size_t ws_size,
                              hipStream_t stream)
{
    (void)in_sizes; (void)n_in; (void)out_size; (void)ws_size;
    const int* word_ids = (const int*)d_in[0];
    const int* in_mask  = (const int*)d_in[1];
    const int* type_ids = (const int*)d_in[2];
    const int* valid    = (const int*)d_in[3];
    const float* word_emb = (const float*)d_in[4];
    const float* pos_emb  = (const float*)d_in[5];
    const float* type_emb = (const float*)d_in[6];
    const float* eg = (const float*)d_in[7];
    const float* eb = (const float*)d_in[8];
    const float* Wq = (const float*)d_in[9];  const float* bq = (const float*)d_in[10];
    const float* Wk = (const float*)d_in[11]; const float* bk = (const float*)d_in[12];
    const float* Wv = (const float*)d_in[13]; const float* bv = (const float*)d_in[14];
    const float* Wo = (const float*)d_in[15]; const float* bo = (const float*)d_in[16];
    const float* ag = (const float*)d_in[17]; const float* ab = (const float*)d_in[18];
    const float* W1 = (const float*)d_in[19]; const float* b1 = (const float*)d_in[20];
    const float* W2 = (const float*)d_in[21]; const float* b2 = (const float*)d_in[22];
    const float* fg = (const float*)d_in[23]; const float* fb = (const float*)d_in[24];
    const float* Wc = (const float*)d_in[25]; const float* bc = (const float*)d_in[26];
    float* out = (float*)d_out;

    // ---- workspace layout (~54.1 MiB; small arrays FIRST) ----
    char* p = (char*)d_ws;
    int* counts = (int*)p;
    int* srcidx = (int*)(p + 1024);
    p += 65536;
    float* x_f32 = (float*)p; p += (size_t)TOKENS * Hdim * 4;
    u16* x_h  = (u16*)p; p += (size_t)TOKENS * Hdim * 2;
    float* tmpf = (float*)p; p += (size_t)TOKENS * Hdim * 4;
    u16* q_h  = (u16*)p;
    u16* k_h  = q_h + (size_t)TOKENS * Hdim;
    u16* v_h  = k_h + (size_t)TOKENS * Hdim;
    u16* c_h  = v_h + (size_t)TOKENS * Hdim;
    u16* h_h  = q_h;   // aliases q/k/v/c (4 * TOKENS*Hdim = TOKENS*FFdim exactly)

    k_embed<<<TOKENS, 256, 0, stream>>>(word_ids, type_ids, word_emb, pos_emb, type_emb, eg, eb, x_f32, x_h);
    k_compact<<<BATCH, 64, 0, stream>>>(valid, counts, srcidx);

    for (int l = 0; l < NLAYER; l++) {
        size_t HH = (size_t)Hdim * Hdim;
        size_t HF = (size_t)Hdim * FFdim;
        k_qkv<<<dim3(6, 32, 3), 256, 0, stream>>>(x_h, Wq + l * HH, Wk + l * HH, Wv + l * HH,
                                                  bq + l * Hdim, bk + l * Hdim, bv + l * Hdim,
                                                  q_h, k_h, v_h);
        k_attn<<<BATCH * NHEAD, 256, 0, stream>>>(q_h, k_h, v_h, in_mask, c_h);
        k_gemm<2><<<dim3(6, 32), 256, 0, stream>>>(c_h, Wo + l * HH, bo + l * Hdim, tmpf, Hdim, Hdim);
        k_addln<<<TOKENS, 256, 0, stream>>>(x_f32, tmpf, ag + l * Hdim, ab + l * Hdim, x_h);
        k_gemm<1><<<dim3(24, 32), 256, 0, stream>>>(x_h, W1 + l * HF, b1 + l * FFdim, h_h, FFdim, Hdim);
        k_gemm<2><<<dim3(6, 32), 256, 0, stream>>>(h_h, W2 + l * HF, b2 + l * Hdim, tmpf, Hdim, FFdim);
        k_addln<<<TOKENS, 256, 0, stream>>>(x_f32, tmpf, fg + l * Hdim, fb + l * Hdim, x_h);
    }
    k_cls<<<TOKENS / 4, 256, 0, stream>>>(x_h, counts, srcidx, Wc, bc, out);
}